// Round 6
// baseline (365.556 us; speedup 1.0000x reference)
//
#include <hip/hip_runtime.h>
#include <hip/hip_bf16.h>

typedef unsigned short u16;
typedef unsigned int   u32;

#define B_N   256
#define S_N   512
#define BSN   (B_N * S_N)      // 131072 positions
#define MEMN  32
#define DKN   128
#define DVN   128
#define DSN   256

typedef __attribute__((ext_vector_type(8))) short bf16x8;
typedef __attribute__((ext_vector_type(4))) float f32x4;
typedef __attribute__((ext_vector_type(2))) float f32x2;

// ---------- helpers ----------
__device__ __forceinline__ float bf2f(u16 u) {
  union { u32 i; float f; } v; v.i = ((u32)u) << 16; return v.f;
}
__device__ __forceinline__ u16 f2bf(float f) {
  union { float f; u32 i; } v; v.f = f;
  u32 x = v.i;
  x += 0x7fffu + ((x >> 16) & 1u);   // RNE
  return (u16)(x >> 16);
}
__device__ __forceinline__ u32 pack2(float a, float b) {
  return (u32)f2bf(a) | ((u32)f2bf(b) << 16);
}
__device__ __forceinline__ float sigmoid_fast(float x) { return 1.f / (1.f + __expf(-x)); }
__device__ __forceinline__ float tanh_fast(float x)    { return 1.f - 2.f / (__expf(2.f * x) + 1.f); }

#define GLOAD_LDS16(g, l)                                         \
  __builtin_amdgcn_global_load_lds(                               \
      (const __attribute__((address_space(1))) void*)(g),         \
      (__attribute__((address_space(3))) void*)(l), 16, 0, 0)

// ============================================================
// kPrep: transpose + bf16-convert weights; build concatenated BqT.
// ============================================================
__global__ __launch_bounds__(256) void kPrep(
    const float* __restrict__ W_sum, const float* __restrict__ W_ab1,
    const float* __restrict__ W_er,  const float* __restrict__ W_ad,
    const float* __restrict__ key_mem, const float* __restrict__ W_df1,
    u16* __restrict__ WsumT, u16* __restrict__ Wab1T,
    u16* __restrict__ WerT,  u16* __restrict__ WaddT,
    u16* __restrict__ BqT)
{
  int e = blockIdx.x * 256 + threadIdx.x;
  if (e < 65536) {
    const int n = e >> 8, k = e & 255;
    WsumT[e] = f2bf(W_sum[k * 256 + n]);
  } else if (e < 131072) {
    e -= 65536;
    const int n = e >> 8, k = e & 255;
    Wab1T[e] = f2bf(W_ab1[k * 256 + n]);
  } else if (e < 147456) {
    e -= 131072;
    const int n = e >> 7, k = e & 127;
    WerT[e] = f2bf(W_er[k * 128 + n]);
  } else if (e < 163840) {
    e -= 147456;
    const int n = e >> 7, k = e & 127;
    WaddT[e] = f2bf(W_ad[k * 128 + n]);
  } else if (e < 184320) {
    e -= 163840;
    const int n = e >> 7, k = e & 127;
    BqT[e] = f2bf(n < 32 ? key_mem[n * 128 + k] : W_df1[k * 128 + (n - 32)]);
  }
}

// ============================================================
// kErAdd v2 (round-5, verified): A in LDS once; B direct from L2.
// ============================================================
__global__ __launch_bounds__(256) void kErAdd(
    const int* __restrict__ qa_data, const float* __restrict__ qa_table,
    const u16* __restrict__ WerT, const u16* __restrict__ WaddT,
    const float* __restrict__ b_er, const float* __restrict__ b_ad,
    u16* __restrict__ eras, u16* __restrict__ addb)
{
  __shared__ __align__(16) u16 As[4 * 128 * 32];   // [chunk][m][k'] 32 KB
  const int tid = threadIdx.x;
  const int p0  = blockIdx.x * 128;

  {
    const int r = tid >> 1, h = tid & 1;
    const long base = (long)qa_data[p0 + r] * DVN + h * 64;
    #pragma unroll
    for (int g = 0; g < 8; ++g) {
      const int k0 = h * 64 + g * 8;
      const float4 fa = *(const float4*)(qa_table + base + g * 8);
      const float4 fb = *(const float4*)(qa_table + base + g * 8 + 4);
      uint4 pk;
      pk.x = pack2(fa.x, fa.y); pk.y = pack2(fa.z, fa.w);
      pk.z = pack2(fb.x, fb.y); pk.w = pack2(fb.z, fb.w);
      *(uint4*)(As + (k0 >> 5) * 4096 + r * 32 + (k0 & 31)) = pk;
    }
  }
  __syncthreads();

  const int lane = tid & 63, wave = tid >> 6;
  const int wr = (wave >> 1) * 64, wc = (wave & 1) * 64;
  const int c15 = lane & 15, q = lane >> 4;

  for (int sel = 0; sel < 2; ++sel) {
    const u16*   Wt = sel ? WaddT : WerT;
    const float* bb = sel ? b_ad  : b_er;
    u16*       outp = sel ? addb  : eras;

    f32x4 acc[4][4];
    #pragma unroll
    for (int b = 0; b < 4; ++b) {
      const float bv = bb[wc + 16 * b + c15];
      #pragma unroll
      for (int a = 0; a < 4; ++a) acc[a][b] = (f32x4){bv, bv, bv, bv};
    }

    #pragma unroll
    for (int c = 0; c < 4; ++c) {
      bf16x8 af[4], bf[4];
      #pragma unroll
      for (int a = 0; a < 4; ++a)
        af[a] = *(const bf16x8*)(As + c * 4096 + (wr + 16 * a + c15) * 32 + q * 8);
      #pragma unroll
      for (int b = 0; b < 4; ++b)
        bf[b] = *(const bf16x8*)(Wt + (wc + 16 * b + c15) * 128 + c * 32 + q * 8);
      #pragma unroll
      for (int a = 0; a < 4; ++a)
        #pragma unroll
        for (int b = 0; b < 4; ++b)
          acc[a][b] = __builtin_amdgcn_mfma_f32_16x16x32_bf16(af[a], bf[b], acc[a][b], 0, 0, 0);
    }

    const int colb = wc + c15;
    #pragma unroll
    for (int a = 0; a < 4; ++a) {
      #pragma unroll
      for (int r = 0; r < 4; ++r) {
        const int row = p0 + wr + 16 * a + 4 * q + r;
        u16* yp = outp + (long)row * DVN + colb;
        #pragma unroll
        for (int b = 0; b < 4; ++b) {
          const float v = sel ? tanh_fast(acc[a][b][r]) : sigmoid_fast(acc[a][b][r]);
          yp[16 * b] = f2bf(v);
        }
      }
    }
  }
}

// ============================================================
// kQe v2 (round-5, verified): BqT direct from L2; only As in LDS.
// ============================================================
__global__ __launch_bounds__(256) void kQe(
    const int* __restrict__ q_data, const float* __restrict__ q_table,
    const u16* __restrict__ BqT,
    const float* __restrict__ bdf1, const float* __restrict__ Wdf2,
    const float* __restrict__ bdf2,
    float* __restrict__ w_all, float* __restrict__ diff,
    u16* __restrict__ sin_buf)
{
  __shared__ __align__(16) u16 As[4 * 128 * 32];   // 32 KB
  const int tid = threadIdx.x;
  const int p0  = blockIdx.x * 128;

  {
    const int r = tid >> 1, h = tid & 1;
    const long base = (long)q_data[p0 + r] * DKN + h * 64;
    #pragma unroll
    for (int g = 0; g < 8; ++g) {
      const int k0 = h * 64 + g * 8;
      const float4 fa = *(const float4*)(q_table + base + g * 8);
      const float4 fb = *(const float4*)(q_table + base + g * 8 + 4);
      uint4 pk;
      pk.x = pack2(fa.x, fa.y); pk.y = pack2(fa.z, fa.w);
      pk.z = pack2(fb.x, fb.y); pk.w = pack2(fb.z, fb.w);
      *(uint4*)(As + (k0 >> 5) * 4096 + r * 32 + (k0 & 31)) = pk;
      *(uint4*)(sin_buf + (long)(p0 + r) * DSN + DKN + k0) = pk;
    }
  }
  __syncthreads();

  const int lane = tid & 63, wave = tid >> 6;
  const int wr = (wave >> 1) * 64, wc = (wave & 1) * 80;
  const int c15 = lane & 15, q = lane >> 4;

  f32x4 acc[4][5];
  float w2v[5];
  #pragma unroll
  for (int b = 0; b < 5; ++b) {
    const int col = wc + 16 * b + c15;
    const float bv = (col < 32) ? 0.f : bdf1[col - 32];
    w2v[b] = (col < 32) ? 0.f : Wdf2[col - 32];
    #pragma unroll
    for (int a = 0; a < 4; ++a) acc[a][b] = (f32x4){bv, bv, bv, bv};
  }

  #pragma unroll
  for (int c = 0; c < 4; ++c) {
    bf16x8 af[4], bf[5];
    #pragma unroll
    for (int a = 0; a < 4; ++a)
      af[a] = *(const bf16x8*)(As + c * 4096 + (wr + 16 * a + c15) * 32 + q * 8);
    #pragma unroll
    for (int b = 0; b < 5; ++b)
      bf[b] = *(const bf16x8*)(BqT + (wc + 16 * b + c15) * 128 + c * 32 + q * 8);
    #pragma unroll
    for (int a = 0; a < 4; ++a)
      #pragma unroll
      for (int b = 0; b < 5; ++b)
        acc[a][b] = __builtin_amdgcn_mfma_f32_16x16x32_bf16(af[a], bf[b], acc[a][b], 0, 0, 0);
  }

  if (wc == 0) {
    #pragma unroll
    for (int a = 0; a < 4; ++a) {
      #pragma unroll
      for (int r = 0; r < 4; ++r) {
        float s0 = acc[a][0][r], s1 = acc[a][1][r];
        float mx = fmaxf(s0, s1);
        mx = fmaxf(mx, __shfl_xor(mx, 1, 64));
        mx = fmaxf(mx, __shfl_xor(mx, 2, 64));
        mx = fmaxf(mx, __shfl_xor(mx, 4, 64));
        mx = fmaxf(mx, __shfl_xor(mx, 8, 64));
        const float e0 = __expf(s0 - mx), e1 = __expf(s1 - mx);
        float sm = e0 + e1;
        sm += __shfl_xor(sm, 1, 64);
        sm += __shfl_xor(sm, 2, 64);
        sm += __shfl_xor(sm, 4, 64);
        sm += __shfl_xor(sm, 8, 64);
        const float inv = 1.f / sm;
        const int row = p0 + wr + 16 * a + 4 * q + r;
        w_all[(long)row * MEMN + c15]      = e0 * inv;
        w_all[(long)row * MEMN + 16 + c15] = e1 * inv;
      }
    }
  }

  float sv[4][4];
  #pragma unroll
  for (int a = 0; a < 4; ++a) {
    #pragma unroll
    for (int r = 0; r < 4; ++r) {
      float s = 0.f;
      #pragma unroll
      for (int b = 0; b < 5; ++b)
        s = fmaf(tanh_fast(acc[a][b][r]), w2v[b], s);
      s += __shfl_xor(s, 1, 64);
      s += __shfl_xor(s, 2, 64);
      s += __shfl_xor(s, 4, 64);
      s += __shfl_xor(s, 8, 64);
      sv[a][r] = s;
    }
  }
  __syncthreads();
  float* red = (float*)As;
  if ((wave & 1) && c15 == 0) {
    #pragma unroll
    for (int a = 0; a < 4; ++a)
      #pragma unroll
      for (int r = 0; r < 4; ++r)
        red[wr + 16 * a + 4 * q + r] = sv[a][r];
  }
  __syncthreads();
  if (!(wave & 1) && c15 == 0) {
    const float bd = bdf2[0];
    #pragma unroll
    for (int a = 0; a < 4; ++a)
      #pragma unroll
      for (int r = 0; r < 4; ++r) {
        const int rr = wr + 16 * a + 4 * q + r;
        diff[p0 + rr] = sv[a][r] + red[rr] + bd;
      }
  }
}

// ============================================================
// kScan v10 (verified): v6 structure + v_pk_fma_f32 packed inner
// arithmetic, bit-identical accumulation order.
// ============================================================
#define CHUNK_BYTES 12288
#define PB_OFF      25088     // 2*CHUNK_BYTES + 512

#define KSTAGE(K, BUF)                                                        \
  {                                                                           \
    const char* wsrc = (const char*)(w_all + (pbase + (long)(K) * 32) * MEMN);\
    const char* esrc = (const char*)(eras + (pbase + (long)(K) * 32) * DVN)   \
                       + ch * 128;                                            \
    const char* asrc = (const char*)(addb + (pbase + (long)(K) * 32) * DVN)   \
                       + ch * 128;                                            \
    char* dst = lds + (BUF) * CHUNK_BYTES;                                    \
    _Pragma("unroll")                                                         \
    for (int r = 0; r < 3; ++r) {                                             \
      const int o = (tid + r * 256) * 16;                                     \
      const char* src;                                                        \
      if (o < 4096) {                                                         \
        src = wsrc + o;                                                       \
      } else if (o < 8192) {                                                  \
        const int f = o - 4096;                                               \
        src = esrc + (f >> 7) * 256 + (f & 127);                              \
      } else {                                                                \
        const int f = o - 8192;                                               \
        src = asrc + (f >> 7) * 256 + (f & 127);                              \
      }                                                                       \
      GLOAD_LDS16(src, dst + o);                                              \
    }                                                                         \
  }

__global__ __launch_bounds__(256) void kScan(
    const float* __restrict__ w_all, const u16* __restrict__ eras,
    const u16* __restrict__ addb, const float* __restrict__ init_mem,
    u16* __restrict__ sin_buf)
{
  __shared__ __align__(16) char lds[PB_OFF + 32768];
  const int tid = threadIdx.x;
  const int ch  = blockIdx.x & 1;
  const int lc  = tid >> 2;
  const int gc  = ch * 64 + lc;
  const int h   = tid & 3;
  const long pbase = (long)(blockIdx.x >> 1) * S_N;

  float* pb = (float*)(lds + PB_OFF);

  // Mv2[p] = {Mv[2p], Mv[2p+1]} in v6 numbering (Mv[m] = slot h*8+m)
  f32x2 Mv2[4];
  #pragma unroll
  for (int p = 0; p < 4; ++p) {
    Mv2[p][0] = init_mem[(h * 8 + 2 * p    ) * DVN + gc];
    Mv2[p][1] = init_mem[(h * 8 + 2 * p + 1) * DVN + gc];
  }

  const int lc2  = tid & 63;
  const int sblk = tid >> 6;
  u16* sp2 = sin_buf + pbase * DSN + ch * 64 + lc2;

  KSTAGE(0, 0)
  for (int k = 0; k < 16; ++k) {
    __syncthreads();
    if (k + 1 < 16) KSTAGE(k + 1, (k + 1) & 1)

    const char*  wb  = lds + (k & 1) * CHUNK_BYTES;
    const f32x4* wl4 = (const f32x4*)wb;
    const u16*   el  = (const u16*)(wb + 4096);
    const u16*   al  = (const u16*)(wb + 8192);

    f32x4 Wr[3][2];
    u16 er[3], ar[3];
    #pragma unroll
    for (int i = 0; i < 2; ++i) Wr[0][i] = wl4[h * 2 + i];
    er[0] = el[lc]; ar[0] = al[lc];
    #pragma unroll
    for (int i = 0; i < 2; ++i) Wr[1][i] = wl4[8 + h * 2 + i];
    er[1] = el[64 + lc]; ar[1] = al[64 + lc];

    #pragma unroll
    for (int s = 0; s < 32; ++s) {
      const int cur = s % 3, nx2 = (s + 2) % 3;
      Wr[nx2][0] = wl4[(s + 2) * 8 + h * 2];
      Wr[nx2][1] = wl4[(s + 2) * 8 + h * 2 + 1];
      er[nx2] = el[(s + 2) * 64 + lc];
      ar[nx2] = al[(s + 2) * 64 + lc];
      {
        // W2[p] pairs w for Mv2[p]: {Wr0.xy, Wr0.zw, Wr1.xy, Wr1.zw}
        f32x2 W2[4];
        W2[0] = (f32x2){Wr[cur][0][0], Wr[cur][0][1]};
        W2[1] = (f32x2){Wr[cur][0][2], Wr[cur][0][3]};
        W2[2] = (f32x2){Wr[cur][1][0], Wr[cur][1][1]};
        W2[3] = (f32x2){Wr[cur][1][2], Wr[cur][1][3]};

        // v6: ac_j = fma(Wr1[j], Mv[4+j], fma(Wr0[j], Mv[j], 0))
        // packed: acc01 = {ac0,ac1}, acc23 = {ac2,ac3} — same order.
        f32x2 z2 = (f32x2){0.f, 0.f};
        f32x2 acc01 = __builtin_elementwise_fma(W2[0], Mv2[0], z2);
        f32x2 acc23 = __builtin_elementwise_fma(W2[1], Mv2[1], z2);
        acc01 = __builtin_elementwise_fma(W2[2], Mv2[2], acc01);
        acc23 = __builtin_elementwise_fma(W2[3], Mv2[3], acc23);
        pb[s * 256 + lc * 4 + h] = (acc01[0] + acc01[1]) + (acc23[0] + acc23[1]);

        const float ec = bf2f(er[cur]);
        const float an = -bf2f(ar[cur]);
        const f32x2 e2  = (f32x2){ec, ec};
        const f32x2 an2 = (f32x2){an, an};
        #pragma unroll
        for (int p = 0; p < 4; ++p) {
          // per element: t = fma(e, m, -a); m = fma(-w, t, m)  (v6 exact)
          f32x2 t = __builtin_elementwise_fma(e2, Mv2[p], an2);
          Mv2[p] = __builtin_elementwise_fma(-W2[p], t, Mv2[p]);
        }
      }
    }

    __syncthreads();
    const int lb = k * 32;
    #pragma unroll
    for (int r = 0; r < 8; ++r) {
      const int s = sblk * 8 + r;
      const f32x4 pv = *(const f32x4*)(pb + s * 256 + lc2 * 4);
      sp2[(long)(lb + s) * DSN] = f2bf((pv[0] + pv[1]) + (pv[2] + pv[3]));
    }
  }
}

// ============================================================
// kSum v3: X staged via async dbuf (8 KB/chunk); W read DIRECT from
// L2 (WsumT is 128 KB, shared by all blocks). Grid linearized 2048
// with pair-swizzle: blocks 2b/2b+1 share the same X rows and run
// adjacently -> second block's X reads hit L2. LDS 32 -> 16 KB.
// ============================================================
#define SSTAGE(XP, C, BUF)                                                  \
  {                                                                         \
    _Pragma("unroll")                                                       \
    for (int u = 0; u < 2; ++u) {                                           \
      const int idx = tid + 256 * u;                                        \
      const int row = idx >> 2, k8 = idx & 3;                               \
      GLOAD_LDS16(XP + (long)(p0 + row) * DSN + (C) * 32 + k8 * 8,          \
                  Ls + (BUF) * 4096 + idx * 8);                             \
    }                                                                       \
  }

__global__ __launch_bounds__(256) void kSum(
    const u16* __restrict__ X, const u16* __restrict__ WsumT,
    const float* __restrict__ bias, u16* __restrict__ Y)
{
  __shared__ __align__(16) u16 Ls[2 * 4096];   // 16 KB: [buf][X 4096]
  const int tid = threadIdx.x;
  const int p0  = (blockIdx.x >> 1) * 128;
  const int j0  = (blockIdx.x & 1) * 128;

  const int lane = tid & 63, wave = tid >> 6;
  const int wr = (wave >> 1) * 64, wc = (wave & 1) * 64;
  const int c15 = lane & 15, q = lane >> 4;

  f32x4 acc[4][4];
  #pragma unroll
  for (int b = 0; b < 4; ++b) {
    const float bv = bias[j0 + wc + 16 * b + c15];
    #pragma unroll
    for (int a = 0; a < 4; ++a) acc[a][b] = (f32x4){bv, bv, bv, bv};
  }

  SSTAGE(X, 0, 0)
  for (int c = 0; c < 8; ++c) {
    __syncthreads();
    if (c + 1 < 8) SSTAGE(X, c + 1, (c + 1) & 1)

    const u16* Ab = Ls + (c & 1) * 4096;
    bf16x8 af[4], bf[4];
    #pragma unroll
    for (int a = 0; a < 4; ++a)
      af[a] = *(const bf16x8*)(Ab + (wr + 16 * a + c15) * 32 + q * 8);
    #pragma unroll
    for (int b = 0; b < 4; ++b)
      bf[b] = *(const bf16x8*)(WsumT + (long)(j0 + wc + 16 * b + c15) * 256 + c * 32 + q * 8);
    #pragma unroll
    for (int a = 0; a < 4; ++a)
      #pragma unroll
      for (int b = 0; b < 4; ++b)
        acc[a][b] = __builtin_amdgcn_mfma_f32_16x16x32_bf16(af[a], bf[b], acc[a][b], 0, 0, 0);
  }

  const int colb = j0 + wc + c15;
  #pragma unroll
  for (int a = 0; a < 4; ++a) {
    #pragma unroll
    for (int r = 0; r < 4; ++r) {
      const int row = p0 + wr + 16 * a + 4 * q + r;
      u16* yp = Y + (long)row * DSN + colb;
      #pragma unroll
      for (int b = 0; b < 4; ++b)
        yp[16 * b] = f2bf(tanh_fast(acc[a][b][r]));
    }
  }
}

// ============================================================
// kAb v3: same treatment as kSum v3 + fused W_ab2 dot.
// ============================================================
__global__ __launch_bounds__(256) void kAb(
    const u16* __restrict__ X, const u16* __restrict__ Wab1T,
    const float* __restrict__ bias, const float* __restrict__ Wab2,
    float* __restrict__ part)
{
  __shared__ __align__(16) u16 Ls[2 * 4096];   // 16 KB
  const int tid = threadIdx.x;
  const int p0  = (blockIdx.x >> 1) * 128;
  const int j0  = (blockIdx.x & 1) * 128;

  const int lane = tid & 63, wave = tid >> 6;
  const int wr = (wave >> 1) * 64, wc = (wave & 1) * 64;
  const int c15 = lane & 15, q = lane >> 4;

  f32x4 acc[4][4];
  float w2v[4];
  #pragma unroll
  for (int b = 0; b < 4; ++b) {
    const int col = j0 + wc + 16 * b + c15;
    const float bv = bias[col];
    w2v[b] = Wab2[col];
    #pragma unroll
    for (int a = 0; a < 4; ++a) acc[a][b] = (f32x4){bv, bv, bv, bv};
  }

  SSTAGE(X, 0, 0)
  for (int c = 0; c < 8; ++c) {
    __syncthreads();
    if (c + 1 < 8) SSTAGE(X, c + 1, (c + 1) & 1)

    const u16* Ab = Ls + (c & 1) * 4096;
    bf16x8 af[4], bf[4];
    #pragma unroll
    for (int a = 0; a < 4; ++a)
      af[a] = *(const bf16x8*)(Ab + (wr + 16 * a + c15) * 32 + q * 8);
    #pragma unroll
    for (int b = 0; b < 4; ++b)
      bf[b] = *(const bf16x8*)(Wab1T + (long)(j0 + wc + 16 * b + c15) * 256 + c * 32 + q * 8);
    #pragma unroll
    for (int a = 0; a < 4; ++a)
      #pragma unroll
      for (int b = 0; b < 4; ++b)
        acc[a][b] = __builtin_amdgcn_mfma_f32_16x16x32_bf16(af[a], bf[b], acc[a][b], 0, 0, 0);
  }

  float sv[4][4];
  #pragma unroll
  for (int a = 0; a < 4; ++a) {
    #pragma unroll
    for (int r = 0; r < 4; ++r) {
      float s = 0.f;
      #pragma unroll
      for (int b = 0; b < 4; ++b)
        s = fmaf(tanh_fast(acc[a][b][r]), w2v[b], s);
      s += __shfl_xor(s, 1, 64);
      s += __shfl_xor(s, 2, 64);
      s += __shfl_xor(s, 4, 64);
      s += __shfl_xor(s, 8, 64);
      sv[a][r] = s;
    }
  }
  __syncthreads();
  float* red = (float*)Ls;
  if ((wave & 1) && c15 == 0) {
    #pragma unroll
    for (int a = 0; a < 4; ++a)
      #pragma unroll
      for (int r = 0; r < 4; ++r)
        red[wr + 16 * a + 4 * q + r] = sv[a][r];
  }
  __syncthreads();
  if (!(wave & 1) && c15 == 0) {
    #pragma unroll
    for (int a = 0; a < 4; ++a)
      #pragma unroll
      for (int r = 0; r < 4; ++r) {
        const int rr = wr + 16 * a + 4 * q + r;
        part[(long)(blockIdx.x & 1) * BSN + p0 + rr] = sv[a][r] + red[rr];
      }
  }
}

// ============================================================
// kOut: combine. grid (BSN/256), block 256. f32 output.
// ============================================================
__global__ __launch_bounds__(256) void kOut(
    const float* __restrict__ part, const float* __restrict__ diff,
    const float* __restrict__ bab2, float* __restrict__ out)
{
  const int p = blockIdx.x * 256 + threadIdx.x;
  const float ab = part[p] + part[BSN + p] + bab2[0];
  const float d  = diff[p];
  const float z  = 3.0f * ab - d;
  out[p]           = sigmoid_fast(z);
  out[BSN + p]     = ab;
  out[2 * BSN + p] = d;
  out[3 * BSN + p] = z;
}

// ============================================================
// launch
// ============================================================
extern "C" void kernel_launch(void* const* d_in, const int* in_sizes, int n_in,
                              void* d_out, int out_size, void* d_ws, size_t ws_size,
                              hipStream_t stream)
{
  const int*   q_data   = (const int*)d_in[0];
  const int*   qa_data  = (const int*)d_in[1];
  const float* q_table  = (const float*)d_in[2];
  const float* qa_table = (const float*)d_in[3];
  const float* key_mem  = (const float*)d_in[4];
  const float* init_mem = (const float*)d_in[5];
  const float* W_erase  = (const float*)d_in[6];
  const float* b_erase  = (const float*)d_in[7];
  const float* W_add    = (const float*)d_in[8];
  const float* b_add    = (const float*)d_in[9];
  const float* W_sum    = (const float*)d_in[10];
  const float* b_sum    = (const float*)d_in[11];
  const float* W_ab1    = (const float*)d_in[12];
  const float* b_ab1    = (const float*)d_in[13];
  const float* W_ab2    = (const float*)d_in[14];
  const float* b_ab2    = (const float*)d_in[15];
  const float* W_df1    = (const float*)d_in[16];
  const float* b_df1    = (const float*)d_in[17];
  const float* W_df2    = (const float*)d_in[18];
  const float* b_df2    = (const float*)d_in[19];

  // workspace layout (bytes); total 152,936,448
  char* ws = (char*)d_ws;
  float* w_all = (float*)(ws + 0);           // [BS][32] f32   16,777,216
  u16*   eras  = (u16*)(ws + 16777216);      // [BS][128] bf16 33,554,432
  u16*   addb  = (u16*)(ws + 50331648);      // [BS][128] bf16 33,554,432
  u16*   sinb  = (u16*)(ws + 83886080);      // [BS][256] bf16 67,108,864
  float* diffb = (float*)(ws + 150994944);   // [BS] f32          524,288
  float* part  = (float*)(ws + 151519232);   // [2][BS] f32     1,048,576
  u16*   WerT  = (u16*)(ws + 152567808);     // 32,768
  u16*   WaddT = (u16*)(ws + 152600576);     // 32,768
  u16*   WsumT = (u16*)(ws + 152633344);     // 131,072
  u16*   Wab1T = (u16*)(ws + 152764416);     // 131,072
  u16*   BqT   = (u16*)(ws + 152895488);     // 160x128 bf16 = 40,960
  u16*   summ  = eras;                       // summary reuses eras+addb

  kPrep<<<dim3(720), 256, 0, stream>>>(W_sum, W_ab1, W_erase, W_add, key_mem, W_df1,
                                       WsumT, Wab1T, WerT, WaddT, BqT);
  kErAdd<<<dim3(BSN / 128), 256, 0, stream>>>(qa_data, qa_table, WerT, WaddT,
                                              b_erase, b_add, eras, addb);
  kQe<<<dim3(BSN / 128), 256, 0, stream>>>(q_data, q_table, BqT, b_df1, W_df2, b_df2,
                                           w_all, diffb, sinb);
  kScan<<<dim3(B_N * 2), 256, 0, stream>>>(w_all, eras, addb, init_mem, sinb);
  kSum<<<dim3(BSN / 64), 256, 0, stream>>>(sinb, WsumT, b_sum, summ);
  kAb<<<dim3(BSN / 64), 256, 0, stream>>>(summ, Wab1T, b_ab1, W_ab2, part);
  kOut<<<dim3(BSN / 256), 256, 0, stream>>>(part, diffb, b_ab2, (float*)d_out);
}

// Round 7
// 340.591 us; speedup vs baseline: 1.0733x; 1.0733x over previous
//
#include <hip/hip_runtime.h>
#include <hip/hip_bf16.h>

typedef unsigned short u16;
typedef unsigned int   u32;

#define B_N   256
#define S_N   512
#define BSN   (B_N * S_N)      // 131072 positions
#define MEMN  32
#define DKN   128
#define DVN   128
#define DSN   256

typedef __attribute__((ext_vector_type(8))) short bf16x8;
typedef __attribute__((ext_vector_type(4))) float f32x4;
typedef __attribute__((ext_vector_type(2))) float f32x2;

// ---------- helpers ----------
__device__ __forceinline__ float bf2f(u16 u) {
  union { u32 i; float f; } v; v.i = ((u32)u) << 16; return v.f;
}
__device__ __forceinline__ u16 f2bf(float f) {
  union { float f; u32 i; } v; v.f = f;
  u32 x = v.i;
  x += 0x7fffu + ((x >> 16) & 1u);   // RNE
  return (u16)(x >> 16);
}
__device__ __forceinline__ u32 pack2(float a, float b) {
  return (u32)f2bf(a) | ((u32)f2bf(b) << 16);
}
__device__ __forceinline__ float sigmoid_fast(float x) { return 1.f / (1.f + __expf(-x)); }
__device__ __forceinline__ float tanh_fast(float x)    { return 1.f - 2.f / (__expf(2.f * x) + 1.f); }

#define GLOAD_LDS16(g, l)                                         \
  __builtin_amdgcn_global_load_lds(                               \
      (const __attribute__((address_space(1))) void*)(g),         \
      (__attribute__((address_space(3))) void*)(l), 16, 0, 0)

// ============================================================
// kPrep: transpose + bf16-convert weights; build concatenated BqT.
// ============================================================
__global__ __launch_bounds__(256) void kPrep(
    const float* __restrict__ W_sum, const float* __restrict__ W_ab1,
    const float* __restrict__ W_er,  const float* __restrict__ W_ad,
    const float* __restrict__ key_mem, const float* __restrict__ W_df1,
    u16* __restrict__ WsumT, u16* __restrict__ Wab1T,
    u16* __restrict__ WerT,  u16* __restrict__ WaddT,
    u16* __restrict__ BqT)
{
  int e = blockIdx.x * 256 + threadIdx.x;
  if (e < 65536) {
    const int n = e >> 8, k = e & 255;
    WsumT[e] = f2bf(W_sum[k * 256 + n]);
  } else if (e < 131072) {
    e -= 65536;
    const int n = e >> 8, k = e & 255;
    Wab1T[e] = f2bf(W_ab1[k * 256 + n]);
  } else if (e < 147456) {
    e -= 131072;
    const int n = e >> 7, k = e & 127;
    WerT[e] = f2bf(W_er[k * 128 + n]);
  } else if (e < 163840) {
    e -= 147456;
    const int n = e >> 7, k = e & 127;
    WaddT[e] = f2bf(W_ad[k * 128 + n]);
  } else if (e < 184320) {
    e -= 163840;
    const int n = e >> 7, k = e & 127;
    BqT[e] = f2bf(n < 32 ? key_mem[n * 128 + k] : W_df1[k * 128 + (n - 32)]);
  }
}

// ============================================================
// kErAdd v3: A in LDS once; B direct from L2 (verified round 5).
// NEW: output interleaved ea[pos][col][{e,a}] bf16 so kScan reads
// one ds_read_b32 per step instead of two ds_read_u16.
// Same values, same compute order -> bit-identical.
// ============================================================
__global__ __launch_bounds__(256) void kErAdd(
    const int* __restrict__ qa_data, const float* __restrict__ qa_table,
    const u16* __restrict__ WerT, const u16* __restrict__ WaddT,
    const float* __restrict__ b_er, const float* __restrict__ b_ad,
    u16* __restrict__ ea)
{
  __shared__ __align__(16) u16 As[4 * 128 * 32];   // [chunk][m][k'] 32 KB
  const int tid = threadIdx.x;
  const int p0  = blockIdx.x * 128;

  {
    const int r = tid >> 1, h = tid & 1;
    const long base = (long)qa_data[p0 + r] * DVN + h * 64;
    #pragma unroll
    for (int g = 0; g < 8; ++g) {
      const int k0 = h * 64 + g * 8;
      const float4 fa = *(const float4*)(qa_table + base + g * 8);
      const float4 fb = *(const float4*)(qa_table + base + g * 8 + 4);
      uint4 pk;
      pk.x = pack2(fa.x, fa.y); pk.y = pack2(fa.z, fa.w);
      pk.z = pack2(fb.x, fb.y); pk.w = pack2(fb.z, fb.w);
      *(uint4*)(As + (k0 >> 5) * 4096 + r * 32 + (k0 & 31)) = pk;
    }
  }
  __syncthreads();

  const int lane = tid & 63, wave = tid >> 6;
  const int wr = (wave >> 1) * 64, wc = (wave & 1) * 64;
  const int c15 = lane & 15, q = lane >> 4;

  for (int sel = 0; sel < 2; ++sel) {
    const u16*   Wt = sel ? WaddT : WerT;
    const float* bb = sel ? b_ad  : b_er;

    f32x4 acc[4][4];
    #pragma unroll
    for (int b = 0; b < 4; ++b) {
      const float bv = bb[wc + 16 * b + c15];
      #pragma unroll
      for (int a = 0; a < 4; ++a) acc[a][b] = (f32x4){bv, bv, bv, bv};
    }

    #pragma unroll
    for (int c = 0; c < 4; ++c) {
      bf16x8 af[4], bf[4];
      #pragma unroll
      for (int a = 0; a < 4; ++a)
        af[a] = *(const bf16x8*)(As + c * 4096 + (wr + 16 * a + c15) * 32 + q * 8);
      #pragma unroll
      for (int b = 0; b < 4; ++b)
        bf[b] = *(const bf16x8*)(Wt + (wc + 16 * b + c15) * 128 + c * 32 + q * 8);
      #pragma unroll
      for (int a = 0; a < 4; ++a)
        #pragma unroll
        for (int b = 0; b < 4; ++b)
          acc[a][b] = __builtin_amdgcn_mfma_f32_16x16x32_bf16(af[a], bf[b], acc[a][b], 0, 0, 0);
    }

    const int colb = wc + c15;
    #pragma unroll
    for (int a = 0; a < 4; ++a) {
      #pragma unroll
      for (int r = 0; r < 4; ++r) {
        const int row = p0 + wr + 16 * a + 4 * q + r;
        u16* yp = ea + (long)row * 256 + colb * 2 + sel;   // interleaved {e,a}
        #pragma unroll
        for (int b = 0; b < 4; ++b) {
          const float v = sel ? tanh_fast(acc[a][b][r]) : sigmoid_fast(acc[a][b][r]);
          yp[32 * b] = f2bf(v);
        }
      }
    }
  }
}

// ============================================================
// kQe v2 (round-5, verified): BqT direct from L2; only As in LDS.
// ============================================================
__global__ __launch_bounds__(256) void kQe(
    const int* __restrict__ q_data, const float* __restrict__ q_table,
    const u16* __restrict__ BqT,
    const float* __restrict__ bdf1, const float* __restrict__ Wdf2,
    const float* __restrict__ bdf2,
    float* __restrict__ w_all, float* __restrict__ diff,
    u16* __restrict__ sin_buf)
{
  __shared__ __align__(16) u16 As[4 * 128 * 32];   // 32 KB
  const int tid = threadIdx.x;
  const int p0  = blockIdx.x * 128;

  {
    const int r = tid >> 1, h = tid & 1;
    const long base = (long)q_data[p0 + r] * DKN + h * 64;
    #pragma unroll
    for (int g = 0; g < 8; ++g) {
      const int k0 = h * 64 + g * 8;
      const float4 fa = *(const float4*)(q_table + base + g * 8);
      const float4 fb = *(const float4*)(q_table + base + g * 8 + 4);
      uint4 pk;
      pk.x = pack2(fa.x, fa.y); pk.y = pack2(fa.z, fa.w);
      pk.z = pack2(fb.x, fb.y); pk.w = pack2(fb.z, fb.w);
      *(uint4*)(As + (k0 >> 5) * 4096 + r * 32 + (k0 & 31)) = pk;
      *(uint4*)(sin_buf + (long)(p0 + r) * DSN + DKN + k0) = pk;
    }
  }
  __syncthreads();

  const int lane = tid & 63, wave = tid >> 6;
  const int wr = (wave >> 1) * 64, wc = (wave & 1) * 80;
  const int c15 = lane & 15, q = lane >> 4;

  f32x4 acc[4][5];
  float w2v[5];
  #pragma unroll
  for (int b = 0; b < 5; ++b) {
    const int col = wc + 16 * b + c15;
    const float bv = (col < 32) ? 0.f : bdf1[col - 32];
    w2v[b] = (col < 32) ? 0.f : Wdf2[col - 32];
    #pragma unroll
    for (int a = 0; a < 4; ++a) acc[a][b] = (f32x4){bv, bv, bv, bv};
  }

  #pragma unroll
  for (int c = 0; c < 4; ++c) {
    bf16x8 af[4], bf[5];
    #pragma unroll
    for (int a = 0; a < 4; ++a)
      af[a] = *(const bf16x8*)(As + c * 4096 + (wr + 16 * a + c15) * 32 + q * 8);
    #pragma unroll
    for (int b = 0; b < 5; ++b)
      bf[b] = *(const bf16x8*)(BqT + (wc + 16 * b + c15) * 128 + c * 32 + q * 8);
    #pragma unroll
    for (int a = 0; a < 4; ++a)
      #pragma unroll
      for (int b = 0; b < 5; ++b)
        acc[a][b] = __builtin_amdgcn_mfma_f32_16x16x32_bf16(af[a], bf[b], acc[a][b], 0, 0, 0);
  }

  if (wc == 0) {
    #pragma unroll
    for (int a = 0; a < 4; ++a) {
      #pragma unroll
      for (int r = 0; r < 4; ++r) {
        float s0 = acc[a][0][r], s1 = acc[a][1][r];
        float mx = fmaxf(s0, s1);
        mx = fmaxf(mx, __shfl_xor(mx, 1, 64));
        mx = fmaxf(mx, __shfl_xor(mx, 2, 64));
        mx = fmaxf(mx, __shfl_xor(mx, 4, 64));
        mx = fmaxf(mx, __shfl_xor(mx, 8, 64));
        const float e0 = __expf(s0 - mx), e1 = __expf(s1 - mx);
        float sm = e0 + e1;
        sm += __shfl_xor(sm, 1, 64);
        sm += __shfl_xor(sm, 2, 64);
        sm += __shfl_xor(sm, 4, 64);
        sm += __shfl_xor(sm, 8, 64);
        const float inv = 1.f / sm;
        const int row = p0 + wr + 16 * a + 4 * q + r;
        w_all[(long)row * MEMN + c15]      = e0 * inv;
        w_all[(long)row * MEMN + 16 + c15] = e1 * inv;
      }
    }
  }

  float sv[4][4];
  #pragma unroll
  for (int a = 0; a < 4; ++a) {
    #pragma unroll
    for (int r = 0; r < 4; ++r) {
      float s = 0.f;
      #pragma unroll
      for (int b = 0; b < 5; ++b)
        s = fmaf(tanh_fast(acc[a][b][r]), w2v[b], s);
      s += __shfl_xor(s, 1, 64);
      s += __shfl_xor(s, 2, 64);
      s += __shfl_xor(s, 4, 64);
      s += __shfl_xor(s, 8, 64);
      sv[a][r] = s;
    }
  }
  __syncthreads();
  float* red = (float*)As;
  if ((wave & 1) && c15 == 0) {
    #pragma unroll
    for (int a = 0; a < 4; ++a)
      #pragma unroll
      for (int r = 0; r < 4; ++r)
        red[wr + 16 * a + 4 * q + r] = sv[a][r];
  }
  __syncthreads();
  if (!(wave & 1) && c15 == 0) {
    const float bd = bdf2[0];
    #pragma unroll
    for (int a = 0; a < 4; ++a)
      #pragma unroll
      for (int r = 0; r < 4; ++r) {
        const int rr = wr + 16 * a + 4 * q + r;
        diff[p0 + rr] = sv[a][r] + red[rr] + bd;
      }
  }
}

// ============================================================
// kScan v11 = v10 + interleaved ea: one ds_read_b32 per step for
// {e,a} (unpack is free: e = u32<<16, a = u32 & 0xffff0000).
// Values and order bit-identical to v10.
// ============================================================
#define CHUNK_BYTES 12288     // w 4KB + ea 8KB
#define PB_OFF      25088     // 2*CHUNK_BYTES + 512

#define KSTAGE(K, BUF)                                                        \
  {                                                                           \
    const char* wsrc  = (const char*)(w_all + (pbase + (long)(K) * 32) * MEMN);\
    const char* easrc = (const char*)ea + (pbase + (long)(K) * 32) * 512      \
                        + ch * 256;                                           \
    char* dst = lds + (BUF) * CHUNK_BYTES;                                    \
    _Pragma("unroll")                                                         \
    for (int r = 0; r < 3; ++r) {                                             \
      const int o = (tid + r * 256) * 16;                                     \
      const char* src;                                                        \
      if (o < 4096) {                                                         \
        src = wsrc + o;                                                       \
      } else {                                                                \
        const int f = o - 4096;                                               \
        src = easrc + (f >> 8) * 512 + (f & 255);                             \
      }                                                                       \
      GLOAD_LDS16(src, dst + o);                                              \
    }                                                                         \
  }

__global__ __launch_bounds__(256) void kScan(
    const float* __restrict__ w_all, const u16* __restrict__ ea,
    const float* __restrict__ init_mem, u16* __restrict__ sin_buf)
{
  __shared__ __align__(16) char lds[PB_OFF + 32768];
  const int tid = threadIdx.x;
  const int ch  = blockIdx.x & 1;
  const int lc  = tid >> 2;
  const int gc  = ch * 64 + lc;
  const int h   = tid & 3;
  const long pbase = (long)(blockIdx.x >> 1) * S_N;

  float* pb = (float*)(lds + PB_OFF);

  // Mv2[p] = {Mv[2p], Mv[2p+1]} in v6 numbering (Mv[m] = slot h*8+m)
  f32x2 Mv2[4];
  #pragma unroll
  for (int p = 0; p < 4; ++p) {
    Mv2[p][0] = init_mem[(h * 8 + 2 * p    ) * DVN + gc];
    Mv2[p][1] = init_mem[(h * 8 + 2 * p + 1) * DVN + gc];
  }

  const int lc2  = tid & 63;
  const int sblk = tid >> 6;
  u16* sp2 = sin_buf + pbase * DSN + ch * 64 + lc2;

  KSTAGE(0, 0)
  for (int k = 0; k < 16; ++k) {
    __syncthreads();
    if (k + 1 < 16) KSTAGE(k + 1, (k + 1) & 1)

    const char*  wb  = lds + (k & 1) * CHUNK_BYTES;
    const f32x4* wl4 = (const f32x4*)wb;
    const u32*   el  = (const u32*)(wb + 4096);   // [32 steps][64 cols] {e,a}

    f32x4 Wr[3][2];
    u32 EA[3];
    #pragma unroll
    for (int i = 0; i < 2; ++i) Wr[0][i] = wl4[h * 2 + i];
    EA[0] = el[lc];
    #pragma unroll
    for (int i = 0; i < 2; ++i) Wr[1][i] = wl4[8 + h * 2 + i];
    EA[1] = el[64 + lc];

    #pragma unroll
    for (int s = 0; s < 32; ++s) {
      const int cur = s % 3, nx2 = (s + 2) % 3;
      Wr[nx2][0] = wl4[(s + 2) * 8 + h * 2];
      Wr[nx2][1] = wl4[(s + 2) * 8 + h * 2 + 1];
      EA[nx2] = el[(s + 2) * 64 + lc];
      {
        // W2[p] pairs w for Mv2[p]: {Wr0.xy, Wr0.zw, Wr1.xy, Wr1.zw}
        f32x2 W2[4];
        W2[0] = (f32x2){Wr[cur][0][0], Wr[cur][0][1]};
        W2[1] = (f32x2){Wr[cur][0][2], Wr[cur][0][3]};
        W2[2] = (f32x2){Wr[cur][1][0], Wr[cur][1][1]};
        W2[3] = (f32x2){Wr[cur][1][2], Wr[cur][1][3]};

        // read partial (v6 order): acc01={ac0,ac1}, acc23={ac2,ac3}
        f32x2 z2 = (f32x2){0.f, 0.f};
        f32x2 acc01 = __builtin_elementwise_fma(W2[0], Mv2[0], z2);
        f32x2 acc23 = __builtin_elementwise_fma(W2[1], Mv2[1], z2);
        acc01 = __builtin_elementwise_fma(W2[2], Mv2[2], acc01);
        acc23 = __builtin_elementwise_fma(W2[3], Mv2[3], acc23);
        pb[s * 256 + lc * 4 + h] = (acc01[0] + acc01[1]) + (acc23[0] + acc23[1]);

        // unpack {e,a}: e = lo bf16, a = hi bf16 (already in high half)
        const u32 eav = EA[cur];
        union { u32 i; float f; } ue, ua;
        ue.i = eav << 16;
        ua.i = eav & 0xffff0000u;
        const float ec = ue.f;
        const float an = -ua.f;
        const f32x2 e2  = (f32x2){ec, ec};
        const f32x2 an2 = (f32x2){an, an};
        #pragma unroll
        for (int p = 0; p < 4; ++p) {
          // per element: t = fma(e, m, -a); m = fma(-w, t, m)  (v6 exact)
          f32x2 t = __builtin_elementwise_fma(e2, Mv2[p], an2);
          Mv2[p] = __builtin_elementwise_fma(-W2[p], t, Mv2[p]);
        }
      }
    }

    __syncthreads();
    const int lb = k * 32;
    #pragma unroll
    for (int r = 0; r < 8; ++r) {
      const int s = sblk * 8 + r;
      const f32x4 pv = *(const f32x4*)(pb + s * 256 + lc2 * 4);
      sp2[(long)(lb + s) * DSN] = f2bf((pv[0] + pv[1]) + (pv[2] + pv[3]));
    }
  }
}

// ============================================================
// kSum v2 (round-5, verified): per-chunk double-buffered async staging.
// ============================================================
#define SSTAGE(XP, WP, C, BUF)                                              \
  {                                                                         \
    _Pragma("unroll")                                                       \
    for (int u = 0; u < 2; ++u) {                                           \
      const int idx = tid + 256 * u;                                        \
      const int row = idx >> 2, k8 = idx & 3;                               \
      GLOAD_LDS16(XP + (long)(p0 + row) * DSN + (C) * 32 + k8 * 8,          \
                  Ls + (BUF) * 8192 + idx * 8);                             \
      GLOAD_LDS16(WP + (long)(j0 + row) * 256 + (C) * 32 + k8 * 8,          \
                  Ls + (BUF) * 8192 + 4096 + idx * 8);                      \
    }                                                                       \
  }

__global__ __launch_bounds__(256) void kSum(
    const u16* __restrict__ X, const u16* __restrict__ WsumT,
    const float* __restrict__ bias, u16* __restrict__ Y)
{
  __shared__ __align__(16) u16 Ls[2 * 8192];   // 32 KB
  const int tid = threadIdx.x;
  const int p0  = blockIdx.x * 128;
  const int j0  = blockIdx.y * 128;

  const int lane = tid & 63, wave = tid >> 6;
  const int wr = (wave >> 1) * 64, wc = (wave & 1) * 64;
  const int c15 = lane & 15, q = lane >> 4;

  f32x4 acc[4][4];
  #pragma unroll
  for (int b = 0; b < 4; ++b) {
    const float bv = bias[j0 + wc + 16 * b + c15];
    #pragma unroll
    for (int a = 0; a < 4; ++a) acc[a][b] = (f32x4){bv, bv, bv, bv};
  }

  SSTAGE(X, WsumT, 0, 0)
  for (int c = 0; c < 8; ++c) {
    __syncthreads();
    if (c + 1 < 8) SSTAGE(X, WsumT, c + 1, (c + 1) & 1)

    const u16* Ab = Ls + (c & 1) * 8192;
    const u16* Bb = Ab + 4096;
    bf16x8 af[4], bf[4];
    #pragma unroll
    for (int a = 0; a < 4; ++a)
      af[a] = *(const bf16x8*)(Ab + (wr + 16 * a + c15) * 32 + q * 8);
    #pragma unroll
    for (int b = 0; b < 4; ++b)
      bf[b] = *(const bf16x8*)(Bb + (wc + 16 * b + c15) * 32 + q * 8);
    #pragma unroll
    for (int a = 0; a < 4; ++a)
      #pragma unroll
      for (int b = 0; b < 4; ++b)
        acc[a][b] = __builtin_amdgcn_mfma_f32_16x16x32_bf16(af[a], bf[b], acc[a][b], 0, 0, 0);
  }

  const int colb = j0 + wc + c15;
  #pragma unroll
  for (int a = 0; a < 4; ++a) {
    #pragma unroll
    for (int r = 0; r < 4; ++r) {
      const int row = p0 + wr + 16 * a + 4 * q + r;
      u16* yp = Y + (long)row * DSN + colb;
      #pragma unroll
      for (int b = 0; b < 4; ++b)
        yp[16 * b] = f2bf(tanh_fast(acc[a][b][r]));
    }
  }
}

// ============================================================
// kAb v2 (round-5, verified) + fused W_ab2 dot.
// ============================================================
__global__ __launch_bounds__(256) void kAb(
    const u16* __restrict__ X, const u16* __restrict__ Wab1T,
    const float* __restrict__ bias, const float* __restrict__ Wab2,
    float* __restrict__ part)
{
  __shared__ __align__(16) u16 Ls[2 * 8192];   // 32 KB
  const int tid = threadIdx.x;
  const int p0  = blockIdx.x * 128;
  const int j0  = blockIdx.y * 128;

  const int lane = tid & 63, wave = tid >> 6;
  const int wr = (wave >> 1) * 64, wc = (wave & 1) * 64;
  const int c15 = lane & 15, q = lane >> 4;

  f32x4 acc[4][4];
  float w2v[4];
  #pragma unroll
  for (int b = 0; b < 4; ++b) {
    const int col = j0 + wc + 16 * b + c15;
    const float bv = bias[col];
    w2v[b] = Wab2[col];
    #pragma unroll
    for (int a = 0; a < 4; ++a) acc[a][b] = (f32x4){bv, bv, bv, bv};
  }

  SSTAGE(X, Wab1T, 0, 0)
  for (int c = 0; c < 8; ++c) {
    __syncthreads();
    if (c + 1 < 8) SSTAGE(X, Wab1T, c + 1, (c + 1) & 1)

    const u16* Ab = Ls + (c & 1) * 8192;
    const u16* Bb = Ab + 4096;
    bf16x8 af[4], bf[4];
    #pragma unroll
    for (int a = 0; a < 4; ++a)
      af[a] = *(const bf16x8*)(Ab + (wr + 16 * a + c15) * 32 + q * 8);
    #pragma unroll
    for (int b = 0; b < 4; ++b)
      bf[b] = *(const bf16x8*)(Bb + (wc + 16 * b + c15) * 32 + q * 8);
    #pragma unroll
    for (int a = 0; a < 4; ++a)
      #pragma unroll
      for (int b = 0; b < 4; ++b)
        acc[a][b] = __builtin_amdgcn_mfma_f32_16x16x32_bf16(af[a], bf[b], acc[a][b], 0, 0, 0);
  }

  float sv[4][4];
  #pragma unroll
  for (int a = 0; a < 4; ++a) {
    #pragma unroll
    for (int r = 0; r < 4; ++r) {
      float s = 0.f;
      #pragma unroll
      for (int b = 0; b < 4; ++b)
        s = fmaf(tanh_fast(acc[a][b][r]), w2v[b], s);
      s += __shfl_xor(s, 1, 64);
      s += __shfl_xor(s, 2, 64);
      s += __shfl_xor(s, 4, 64);
      s += __shfl_xor(s, 8, 64);
      sv[a][r] = s;
    }
  }
  __syncthreads();
  float* red = (float*)Ls;
  if ((wave & 1) && c15 == 0) {
    #pragma unroll
    for (int a = 0; a < 4; ++a)
      #pragma unroll
      for (int r = 0; r < 4; ++r)
        red[wr + 16 * a + 4 * q + r] = sv[a][r];
  }
  __syncthreads();
  if (!(wave & 1) && c15 == 0) {
    #pragma unroll
    for (int a = 0; a < 4; ++a)
      #pragma unroll
      for (int r = 0; r < 4; ++r) {
        const int rr = wr + 16 * a + 4 * q + r;
        part[(long)blockIdx.y * BSN + p0 + rr] = sv[a][r] + red[rr];
      }
  }
}

// ============================================================
// kOut: combine. grid (BSN/256), block 256. f32 output.
// ============================================================
__global__ __launch_bounds__(256) void kOut(
    const float* __restrict__ part, const float* __restrict__ diff,
    const float* __restrict__ bab2, float* __restrict__ out)
{
  const int p = blockIdx.x * 256 + threadIdx.x;
  const float ab = part[p] + part[BSN + p] + bab2[0];
  const float d  = diff[p];
  const float z  = 3.0f * ab - d;
  out[p]           = sigmoid_fast(z);
  out[BSN + p]     = ab;
  out[2 * BSN + p] = d;
  out[3 * BSN + p] = z;
}

// ============================================================
// launch
// ============================================================
extern "C" void kernel_launch(void* const* d_in, const int* in_sizes, int n_in,
                              void* d_out, int out_size, void* d_ws, size_t ws_size,
                              hipStream_t stream)
{
  const int*   q_data   = (const int*)d_in[0];
  const int*   qa_data  = (const int*)d_in[1];
  const float* q_table  = (const float*)d_in[2];
  const float* qa_table = (const float*)d_in[3];
  const float* key_mem  = (const float*)d_in[4];
  const float* init_mem = (const float*)d_in[5];
  const float* W_erase  = (const float*)d_in[6];
  const float* b_erase  = (const float*)d_in[7];
  const float* W_add    = (const float*)d_in[8];
  const float* b_add    = (const float*)d_in[9];
  const float* W_sum    = (const float*)d_in[10];
  const float* b_sum    = (const float*)d_in[11];
  const float* W_ab1    = (const float*)d_in[12];
  const float* b_ab1    = (const float*)d_in[13];
  const float* W_ab2    = (const float*)d_in[14];
  const float* b_ab2    = (const float*)d_in[15];
  const float* W_df1    = (const float*)d_in[16];
  const float* b_df1    = (const float*)d_in[17];
  const float* W_df2    = (const float*)d_in[18];
  const float* b_df2    = (const float*)d_in[19];

  // workspace layout (bytes); total 152,936,448
  char* ws = (char*)d_ws;
  float* w_all = (float*)(ws + 0);           // [BS][32] f32      16,777,216
  u16*   ea    = (u16*)(ws + 16777216);      // [BS][128][2] bf16 67,108,864
  u16*   sinb  = (u16*)(ws + 83886080);      // [BS][256] bf16    67,108,864
  float* diffb = (float*)(ws + 150994944);   // [BS] f32             524,288
  float* part  = (float*)(ws + 151519232);   // [2][BS] f32        1,048,576
  u16*   WerT  = (u16*)(ws + 152567808);     // 32,768
  u16*   WaddT = (u16*)(ws + 152600576);     // 32,768
  u16*   WsumT = (u16*)(ws + 152633344);     // 131,072
  u16*   Wab1T = (u16*)(ws + 152764416);     // 131,072
  u16*   BqT   = (u16*)(ws + 152895488);     // 160x128 bf16 = 40,960
  u16*   summ  = ea;                         // summary reuses ea (dead after kScan)

  kPrep<<<dim3(720), 256, 0, stream>>>(W_sum, W_ab1, W_erase, W_add, key_mem, W_df1,
                                       WsumT, Wab1T, WerT, WaddT, BqT);
  kErAdd<<<dim3(BSN / 128), 256, 0, stream>>>(qa_data, qa_table, WerT, WaddT,
                                              b_erase, b_add, ea);
  kQe<<<dim3(BSN / 128), 256, 0, stream>>>(q_data, q_table, BqT, b_df1, W_df2, b_df2,
                                           w_all, diffb, sinb);
  kScan<<<dim3(B_N * 2), 256, 0, stream>>>(w_all, ea, init_mem, sinb);
  kSum<<<dim3(BSN / 128, 2), 256, 0, stream>>>(sinb, WsumT, b_sum, summ);
  kAb<<<dim3(BSN / 128, 2), 256, 0, stream>>>(summ, Wab1T, b_ab1, W_ab2, part);
  kOut<<<dim3(BSN / 256), 256, 0, stream>>>(part, diffb, b_ab2, (float*)d_out);
}